// Round 5
// baseline (228.869 us; speedup 1.0000x reference)
//
#include <hip/hip_runtime.h>
#include <hip/hip_cooperative_groups.h>
#include <math.h>

namespace cg = cooperative_groups;

// LazyEqProp closed form (verified rounds 1-4):
//   E  = x @ We^T + be
//   m0 = mean|E|  > eps ;  H0 = m0 * 0.5*tanh(E  @ W0^T + b0)
//   m1 = mean|H0| > eps ;  H1 = m1 * 0.5*tanh(H0 @ W1^T + b1)
//   m2 = mean|H1| > eps ;  H2 = m2 * 0.5*tanh(H1 @ W2^T + b2)
//   out = H2 @ Wh^T + bh
//
// Round 5: ONE cooperative dispatch (grid 256 x 512 = 1 block/CU).
//   phase A: zero msum, convert x+We -> swizzled f16
//   phase B: gemm E (emit |row| sums); then convert W+Wh (HBM stream hides
//            under other blocks' gemm tails)
//   phases C/D/E: layer gemms with fused mask epilogue + emit
//   phase F: head gemm -> f32 out (128 blocks)
// GEMM internals identical to round 4 (proven): 8 waves, wave tile 32x32,
// global_load_lds width-16 staging into double-buffered LDS, one barrier per
// K-step, pre-swizzled global layout => conflict-free ds_read_b128.

using half_t = _Float16;
typedef _Float16 f16x4 __attribute__((ext_vector_type(4)));
typedef _Float16 f16x8 __attribute__((ext_vector_type(8)));
typedef float    f32x4 __attribute__((ext_vector_type(4)));

constexpr int KDIM = 1024;
constexpr int ROWB = KDIM * 2;  // bytes per swizzled f16 row
constexpr float EPS_GATE = 0.01f;

__device__ __forceinline__ float tanh_fast(float z) {
    return 1.0f - 2.0f / (__expf(2.0f * z) + 1.0f);  // safe at +-inf
}

__device__ __forceinline__ void gload16(const void* g, void* l) {
    __builtin_amdgcn_global_load_lds(
        (const __attribute__((address_space(1))) void*)g,
        (__attribute__((address_space(3))) void*)l, 16, 0, 0);
}

// convert one fp32 row to swizzled f16 (256-lane group: sub = 0..255)
__device__ __forceinline__ void conv_row(const float* __restrict__ src,
                                         half_t* __restrict__ dst,
                                         int row, int sub) {
    const f32x4 v = *(const f32x4*)(src + (size_t)row * KDIM + 4 * sub);
    f16x4 h;
    h[0] = (half_t)v[0]; h[1] = (half_t)v[1]; h[2] = (half_t)v[2]; h[3] = (half_t)v[3];
    const int p = (8 * sub) ^ ((row & 7) << 4);
    *(f16x4*)((char*)dst + (size_t)row * ROWB + p) = h;
}

// ---- NT gemm tile: O[m,n] = epi( sum_k P[m,k]*Q[n,k] + bias[n] )
// Tile 128m x 64n x 64k; 8 waves (4m x 2n), wave tile 32x32.
// EPI: 0 = bias -> swz f16; 1 = mask(msum_in)*0.5*tanh(.+bias) -> swz f16;
//      2 = bias -> f32.  EMIT: atomicAdd per-row |out| partials into msum_out.
template <int EPI, bool EMIT>
__device__ __forceinline__
void gemm_tile(char* __restrict__ smem, int tid, int m0, int n0,
               const half_t* __restrict__ P, const half_t* __restrict__ Q,
               const float* __restrict__ bias, const float* __restrict__ msum_in,
               float* __restrict__ msum_out, void* __restrict__ Out, int Nout) {
    const char* gP0 = (const char*)P + (size_t)(m0 + (tid >> 3)) * ROWB + (tid & 7) * 16;
    const char* gP1 = gP0 + (size_t)64 * ROWB;
    const char* gQ  = (const char*)Q + (size_t)(n0 + (tid >> 3)) * ROWB + (tid & 7) * 16;
    const int ldsT = tid * 16;

    const int lane = tid & 63;
    const int w = tid >> 6;
    const int wm = (w & 3) * 32;
    const int wn = (w >> 2) * 32;
    const int l15 = lane & 15, l4 = lane >> 4;
    const int off0 = (l4 * 16) ^ ((lane & 7) << 4);
    const int off1 = off0 ^ 64;

    f32x4 acc[2][2] = {};  // [n-frag][m-frag]

    // prologue: stage tile 0 into buf 0
    gload16(gP0, smem + ldsT);
    gload16(gP1, smem + 8192 + ldsT);
    gload16(gQ, smem + 32768 + ldsT);

    for (int s = 0; s < 16; ++s) {
        const int bsel = s & 1;
        __syncthreads();  // drains vmcnt(0): buf bsel ready; buf bsel^1 reads done
        if (s < 15) {     // stage tile s+1 into other buf (lands during MFMA)
            const int go = (s + 1) * 128;
            const int bp = (bsel ^ 1) * 16384, bq = 32768 + (bsel ^ 1) * 8192;
            gload16(gP0 + go, smem + bp + ldsT);
            gload16(gP1 + go, smem + bp + 8192 + ldsT);
            gload16(gQ + go, smem + bq + ldsT);
        }
        const char* PtB = smem + bsel * 16384;
        const char* QtB = smem + 32768 + bsel * 8192;
#pragma unroll
        for (int h = 0; h < 2; ++h) {
            const int ko = h ? off1 : off0;
            f16x8 qa[2], pb[2];
#pragma unroll
            for (int i = 0; i < 2; ++i)
                qa[i] = *(const f16x8*)(QtB + (wn + i * 16 + l15) * 128 + ko);
#pragma unroll
            for (int j = 0; j < 2; ++j)
                pb[j] = *(const f16x8*)(PtB + (wm + j * 16 + l15) * 128 + ko);
#pragma unroll
            for (int i = 0; i < 2; ++i)
#pragma unroll
                for (int j = 0; j < 2; ++j)
                    acc[i][j] = __builtin_amdgcn_mfma_f32_16x16x32_f16(qa[i], pb[j], acc[i][j], 0, 0, 0);
        }
    }

    // epilogue: lane holds m = m0+wm+j*16+l15, n = n0+wn+i*16+l4*4+e
#pragma unroll
    for (int j = 0; j < 2; ++j) {
        const int m = m0 + wm + j * 16 + l15;
        float msk = 1.0f;
        if (EPI == 1) msk = (msum_in[m] * (1.0f / 1024.0f) > EPS_GATE) ? 1.0f : 0.0f;
        float rsum = 0.0f;
#pragma unroll
        for (int i = 0; i < 2; ++i) {
            const int n = n0 + wn + i * 16 + l4 * 4;
            const f32x4 bz = *(const f32x4*)(bias + n);
            float v[4];
#pragma unroll
            for (int e = 0; e < 4; ++e) {
                v[e] = acc[i][j][e] + bz[e];
                if (EPI == 1) v[e] = msk * (0.5f * tanh_fast(v[e]));
                if (EMIT) rsum += fabsf(v[e]);
            }
            if (EPI == 2) {
                f32x4 o; o[0] = v[0]; o[1] = v[1]; o[2] = v[2]; o[3] = v[3];
                *(f32x4*)((float*)Out + (size_t)m * Nout + n) = o;
            } else {
                f16x4 hv;
                hv[0] = (half_t)v[0]; hv[1] = (half_t)v[1];
                hv[2] = (half_t)v[2]; hv[3] = (half_t)v[3];
                const int p = (n * 2) ^ ((m & 7) << 4);
                *(f16x4*)((char*)Out + (size_t)m * ROWB + p) = hv;
            }
        }
        if (EMIT) {  // reduce over the 4 l4-lanes sharing this row, one atomic
            rsum += __shfl_xor(rsum, 16, 64);
            rsum += __shfl_xor(rsum, 32, 64);
            if (l4 == 0) atomicAdd(msum_out + m, rsum);
        }
    }
}

__global__ __launch_bounds__(512)
void fused_all(const float* __restrict__ x,  const float* __restrict__ We,
               const float* __restrict__ be, const float* __restrict__ W,
               const float* __restrict__ b,  const float* __restrict__ Wh,
               const float* __restrict__ bh,
               half_t* __restrict__ s0, half_t* __restrict__ s1,
               half_t* __restrict__ We16, half_t* __restrict__ W16,
               half_t* __restrict__ Wh16, float* __restrict__ msum,
               float* __restrict__ out) {
    __shared__ alignas(16) char smem[49152];
    cg::grid_group grid = cg::this_grid();
    const int tid = threadIdx.x;
    const int bid = blockIdx.x;
    const int sub = tid & 255;
    const int hi  = tid >> 8;

    // ---- phase A: zero msum (blocks 0-2) + convert x (2048 rows), We (1024)
    if (bid < 3) ((f32x4*)msum)[bid * 512 + tid] = f32x4{0.f, 0.f, 0.f, 0.f};
#pragma unroll
    for (int i = 0; i < 6; ++i) {
        const int r = bid * 12 + 2 * i + hi;  // [0, 3072)
        if (r < 2048) conv_row(x, s0, r, sub);
        else          conv_row(We, We16, r - 2048, sub);
    }
    grid.sync();

    // tile map (XCD-aware): xcd = bid&7 owns m-tiles {2x,2x+1}
    const int m0 = ((bid & 7) * 2 + ((bid >> 3) & 1)) * 128;
    const int n0 = (bid >> 4) * 64;

    // ---- phase B: E = x @ We^T + be (emit msum0); then convert W (3072), Wh (512)
    gemm_tile<0, true>(smem, tid, m0, n0, s0, We16, be, nullptr, msum, s1, KDIM);
#pragma unroll
    for (int i = 0; i < 7; ++i) {
        const int r = bid * 14 + 2 * i + hi;  // [0, 3584)
        if (r < 3072) conv_row(W, W16, r, sub);
        else          conv_row(Wh, Wh16, r - 3072, sub);
    }
    grid.sync();

    // ---- phase C: H0 = m0 * 0.5*tanh(E @ W0^T + b0); emit msum1
    gemm_tile<1, true>(smem, tid, m0, n0, s1, W16, b, msum, msum + 2048, s0, KDIM);
    grid.sync();

    // ---- phase D: H1; emit msum2
    gemm_tile<1, true>(smem, tid, m0, n0, s0, W16 + (size_t)KDIM * KDIM, b + KDIM,
                       msum + 2048, msum + 4096, s1, KDIM);
    grid.sync();

    // ---- phase E: H2 (no emit)
    gemm_tile<1, false>(smem, tid, m0, n0, s1, W16 + (size_t)2 * KDIM * KDIM,
                        b + 2 * KDIM, msum + 4096, nullptr, s0, KDIM);
    grid.sync();

    // ---- phase F: head (2048 x 512): 16 m-tiles x 8 n-tiles = 128 blocks
    if (bid < 128) {
        gemm_tile<2, false>(smem, tid, m0, n0, s0, Wh16, bh, nullptr, nullptr, out, 512);
    }
}

extern "C" void kernel_launch(void* const* d_in, const int* in_sizes, int n_in,
                              void* d_out, int out_size, void* d_ws, size_t ws_size,
                              hipStream_t stream) {
    const float* x  = (const float*)d_in[0];  // [2048,1024]
    const float* We = (const float*)d_in[1];  // [1024,1024]
    const float* be = (const float*)d_in[2];  // [1024]
    const float* W  = (const float*)d_in[3];  // [3,1024,1024]
    const float* b  = (const float*)d_in[4];  // [3,1024]
    const float* Wh = (const float*)d_in[5];  // [512,1024]
    const float* bh = (const float*)d_in[6];  // [512]

    const int B = 2048, H = 1024, O = 512;

    half_t* s0   = (half_t*)d_ws;                   // x16 / H0 / H2
    half_t* s1   = s0 + (size_t)B * H;              // E / H1
    half_t* We16 = s1 + (size_t)B * H;
    half_t* W16  = We16 + (size_t)H * H;
    half_t* Wh16 = W16 + (size_t)3 * H * H;
    float*  msum = (float*)(Wh16 + (size_t)O * H);  // 3 x 2048 f32
    float*  out  = (float*)d_out;

    void* args[] = {(void*)&x, (void*)&We, (void*)&be, (void*)&W, (void*)&b,
                    (void*)&Wh, (void*)&bh, (void*)&s0, (void*)&s1, (void*)&We16,
                    (void*)&W16, (void*)&Wh16, (void*)&msum, (void*)&out};
    hipLaunchCooperativeKernel((void*)fused_all, dim3(256), dim3(512), args, 0, stream);
}

// Round 6
// 54.852 us; speedup vs baseline: 4.1725x; 4.1725x over previous
//
#include <hip/hip_runtime.h>
#include <math.h>

// LazyEqProp closed form (verified rounds 1-5):
//   E  = x @ We^T + be
//   m0 = mean|E|  > eps ;  H0 = m0 * 0.5*tanh(E  @ W0^T + b0)
//   m1 = mean|H0| > eps ;  H1 = m1 * 0.5*tanh(H0 @ W1^T + b1)
//   m2 = mean|H1| > eps ;  H2 = m2 * 0.5*tanh(H1 @ W2^T + b2)
//   out = H2 @ Wh^T + bh
//
// Round 6: round-4 six-dispatch structure (cooperative grid.sync was ~30us
// per sync -> reverted). GEMM K-loop upgraded to T3/T4-lite:
//  - TRIPLE-buffered LDS (3 x 24 KB), prefetch depth 2
//  - raw s_barrier + counted s_waitcnt vmcnt(3) (never drain to 0 mid-loop)
//  - s_setprio(1) around the MFMA cluster (T5)
// Everything else byte-identical to round 4 (proven: swizzled f16 global
// layout, global_load_lds width-16 linear staging, 8 waves, wave tile 32x32,
// fused mask epilogue + atomicAdd row-sum emission).

using half_t = _Float16;
typedef _Float16 f16x4 __attribute__((ext_vector_type(4)));
typedef _Float16 f16x8 __attribute__((ext_vector_type(8)));
typedef float    f32x4 __attribute__((ext_vector_type(4)));

constexpr int KDIM = 1024;
constexpr int ROWB = KDIM * 2;  // bytes per swizzled f16 row
constexpr float EPS_GATE = 0.01f;

__device__ __forceinline__ float tanh_fast(float z) {
    return 1.0f - 2.0f / (__expf(2.0f * z) + 1.0f);  // safe at +-inf
}

__device__ __forceinline__ void gload16(const void* g, void* l) {
    __builtin_amdgcn_global_load_lds(
        (const __attribute__((address_space(1))) void*)g,
        (__attribute__((address_space(3))) void*)l, 16, 0, 0);
}

// ---- fp32 -> swizzled fp16 (row r, byte p holds element (p ^ ((r&7)<<4))/2)
//      + zero the 3 row-sum accumulators (blocks 0..5)
__global__ __launch_bounds__(256)
void convert_all(const float* __restrict__ x,  const float* __restrict__ We,
                 const float* __restrict__ W,  const float* __restrict__ Wh,
                 half_t* __restrict__ x16, half_t* __restrict__ We16,
                 half_t* __restrict__ W16, half_t* __restrict__ Wh16,
                 float* __restrict__ msum) {
    const int bid = blockIdx.x;
    const int t = threadIdx.x;
    if (bid < 6) ((f32x4*)msum)[bid * 256 + t] = f32x4{0.f, 0.f, 0.f, 0.f};
    const float* src; half_t* dst; int row;
    if (bid < 2048)      { src = x;  dst = x16;  row = bid; }
    else if (bid < 3072) { src = We; dst = We16; row = bid - 2048; }
    else if (bid < 6144) { src = W;  dst = W16;  row = bid - 3072; }
    else                 { src = Wh; dst = Wh16; row = bid - 6144; }
    const f32x4 v = *(const f32x4*)(src + (size_t)row * KDIM + 4 * t);
    f16x4 h;
    h[0] = (half_t)v[0]; h[1] = (half_t)v[1]; h[2] = (half_t)v[2]; h[3] = (half_t)v[3];
    const int p = (8 * t) ^ ((row & 7) << 4);
    *(f16x4*)((char*)dst + (size_t)row * ROWB + p) = h;
}

// ---- NT gemm: O[m,n] = epi( sum_k P[m,k]*Q[n,k] + bias[n] )
// P,Q swizzled f16. Tile 128m x 64n x 64k; 8 waves (4m x 2n), wave tile 32x32.
// EPI: 0 = bias -> swz f16; 1 = mask(msum_in)*0.5*tanh(.+bias) -> swz f16;
//      2 = bias -> f32.  EMIT: atomicAdd per-row |out| partials into msum_out.
template <int EPI, bool EMIT>
__global__ __launch_bounds__(512)
void gemm8w(const half_t* __restrict__ P, const half_t* __restrict__ Q,
            const float* __restrict__ bias, const float* __restrict__ msum_in,
            float* __restrict__ msum_out, void* __restrict__ Out, int Nout) {
    // 3 buffers x (P 16 KB | Q 8 KB) = 72 KB (gfx950 LDS 160 KB)
    __shared__ alignas(16) char smem[3 * 24576];

    const int tid = threadIdx.x;
    const int bid = blockIdx.x;
    // XCD-aware: xcd = bid&7 owns m-tiles {2x,2x+1} across all n-tiles.
    const int m0 = ((bid & 7) * 2 + ((bid >> 3) & 1)) * 128;
    const int n0 = (bid >> 4) * 64;

    // staging: 3 x 16B granules/thread, LDS dest = uniform base + tid*16
    const char* gP0 = (const char*)P + (size_t)(m0 + (tid >> 3)) * ROWB + (tid & 7) * 16;
    const char* gP1 = gP0 + (size_t)64 * ROWB;
    const char* gQ  = (const char*)Q + (size_t)(n0 + (tid >> 3)) * ROWB + (tid & 7) * 16;
    const int ldsT = tid * 16;

    const int lane = tid & 63;
    const int w = tid >> 6;
    const int wm = (w & 3) * 32;
    const int wn = (w >> 2) * 32;
    const int l15 = lane & 15, l4 = lane >> 4;
    const int off0 = (l4 * 16) ^ ((lane & 7) << 4);
    const int off1 = off0 ^ 64;

    f32x4 acc[2][2] = {};  // [n-frag][m-frag]

    auto stage = [&](int s) {
        const int go = s * 128;
        char* base = smem + (s % 3) * 24576;
        gload16(gP0 + go, base + ldsT);
        gload16(gP1 + go, base + 8192 + ldsT);
        gload16(gQ + go, base + 16384 + ldsT);
    };

    // prologue: tiles 0 and 1 in flight (6 outstanding VMEM / wave)
    stage(0);
    stage(1);

    for (int s = 0; s < 16; ++s) {
        // wait: own DMAs for tile s done (tile s+1's 3 may stay in flight);
        // in-order vmcnt completion makes this robust to stray later loads.
        if (s == 15) asm volatile("s_waitcnt vmcnt(0)" ::: "memory");
        else         asm volatile("s_waitcnt vmcnt(3)" ::: "memory");
        __builtin_amdgcn_s_barrier();   // now ALL waves' tile-s DMAs landed
        asm volatile("" ::: "memory");  // fence: keep stage() below barrier
        if (s < 14) stage(s + 2);       // overwrites buf((s-1)%3): safe now
        const char* PtB = smem + (s % 3) * 24576;
        const char* QtB = PtB + 16384;
        __builtin_amdgcn_s_setprio(1);
#pragma unroll
        for (int h = 0; h < 2; ++h) {
            const int ko = h ? off1 : off0;
            f16x8 qa[2], pb[2];
#pragma unroll
            for (int i = 0; i < 2; ++i)
                qa[i] = *(const f16x8*)(QtB + (wn + i * 16 + l15) * 128 + ko);
#pragma unroll
            for (int j = 0; j < 2; ++j)
                pb[j] = *(const f16x8*)(PtB + (wm + j * 16 + l15) * 128 + ko);
#pragma unroll
            for (int i = 0; i < 2; ++i)
#pragma unroll
                for (int j = 0; j < 2; ++j)
                    acc[i][j] = __builtin_amdgcn_mfma_f32_16x16x32_f16(qa[i], pb[j], acc[i][j], 0, 0, 0);
        }
        __builtin_amdgcn_s_setprio(0);
    }

    // ---- epilogue: lane holds m = m0+wm+j*16+l15, n = n0+wn+i*16+l4*4+e
#pragma unroll
    for (int j = 0; j < 2; ++j) {
        const int m = m0 + wm + j * 16 + l15;
        float msk = 1.0f;
        if (EPI == 1) msk = (msum_in[m] * (1.0f / 1024.0f) > EPS_GATE) ? 1.0f : 0.0f;
        float rsum = 0.0f;
#pragma unroll
        for (int i = 0; i < 2; ++i) {
            const int n = n0 + wn + i * 16 + l4 * 4;
            const f32x4 bz = *(const f32x4*)(bias + n);
            float v[4];
#pragma unroll
            for (int e = 0; e < 4; ++e) {
                v[e] = acc[i][j][e] + bz[e];
                if (EPI == 1) v[e] = msk * (0.5f * tanh_fast(v[e]));
                if (EMIT) rsum += fabsf(v[e]);
            }
            if (EPI == 2) {
                f32x4 o; o[0] = v[0]; o[1] = v[1]; o[2] = v[2]; o[3] = v[3];
                *(f32x4*)((float*)Out + (size_t)m * Nout + n) = o;
            } else {
                f16x4 hv;
                hv[0] = (half_t)v[0]; hv[1] = (half_t)v[1];
                hv[2] = (half_t)v[2]; hv[3] = (half_t)v[3];
                const int p = (n * 2) ^ ((m & 7) << 4);
                *(f16x4*)((char*)Out + (size_t)m * ROWB + p) = hv;
            }
        }
        if (EMIT) {  // reduce over the 4 l4-lanes sharing this row, one atomic
            rsum += __shfl_xor(rsum, 16, 64);
            rsum += __shfl_xor(rsum, 32, 64);
            if (l4 == 0) atomicAdd(msum_out + m, rsum);
        }
    }
}

extern "C" void kernel_launch(void* const* d_in, const int* in_sizes, int n_in,
                              void* d_out, int out_size, void* d_ws, size_t ws_size,
                              hipStream_t stream) {
    const float* x  = (const float*)d_in[0];  // [2048,1024]
    const float* We = (const float*)d_in[1];  // [1024,1024]
    const float* be = (const float*)d_in[2];  // [1024]
    const float* W  = (const float*)d_in[3];  // [3,1024,1024]
    const float* b  = (const float*)d_in[4];  // [3,1024]
    const float* Wh = (const float*)d_in[5];  // [512,1024]
    const float* bh = (const float*)d_in[6];  // [512]

    const int B = 2048, H = 1024, O = 512;

    half_t* s0   = (half_t*)d_ws;                   // x16 / H0 / H2
    half_t* s1   = s0 + (size_t)B * H;              // E / H1
    half_t* We16 = s1 + (size_t)B * H;
    half_t* W16  = We16 + (size_t)H * H;
    half_t* Wh16 = W16 + (size_t)3 * H * H;
    float*  msum = (float*)(Wh16 + (size_t)O * H);  // 3 x 2048 f32
    float*  out  = (float*)d_out;

    convert_all<<<6656, 256, 0, stream>>>(x, We, W, Wh, s0, We16, W16, Wh16, msum);

    // E = x @ We^T + be; emit |E| row sums -> msum0
    gemm8w<0, true ><<<256, 512, 0, stream>>>(s0, We16, be, nullptr, msum, s1, H);
    // H0 = m0 * 0.5*tanh(E @ W0^T + b0); emit -> msum1
    gemm8w<1, true ><<<256, 512, 0, stream>>>(s1, W16, b, msum, msum + 2048, s0, H);
    // H1; emit -> msum2
    gemm8w<1, true ><<<256, 512, 0, stream>>>(s0, W16 + (size_t)H * H, b + H,
                                              msum + 2048, msum + 4096, s1, H);
    // H2 (no emit)
    gemm8w<1, false><<<256, 512, 0, stream>>>(s1, W16 + (size_t)2 * H * H, b + 2 * H,
                                              msum + 4096, nullptr, s0, H);
    // head
    gemm8w<2, false><<<128, 512, 0, stream>>>(s0, Wh16, bh, nullptr, nullptr, out, O);
}